// Round 2
// baseline (116.446 us; speedup 1.0000x reference)
//
#include <hip/hip_runtime.h>

#define BB 8
#define SS 2048
#define DD 128

typedef _Float16 f16;
typedef _Float16 f16x8 __attribute__((ext_vector_type(8)));
typedef float f32x4 __attribute__((ext_vector_type(4)));

static __device__ __forceinline__ unsigned short f2h(float x) {
    f16 h = (f16)x;
    return __builtin_bit_cast(unsigned short, h);
}

static __device__ __forceinline__ float fast_exp2(float x) {
#if __has_builtin(__builtin_amdgcn_exp2f)
    return __builtin_amdgcn_exp2f(x);
#else
    return exp2f(x);
#endif
}

// ---------------------------------------------------------------------------
// Flash attention forward, causal. f16 MFMA 16x16x32, fp32 softmax/accum.
// Block: 256 threads = 4 waves; each wave owns 16 q rows (QBLK=64 per block).
// KV tiles of 64 keys.
// K  LDS: row-major [64][128],  el = row*128 + (col ^ ((row&7)<<3))   (f16)
// Vt LDS: TRANSPOSED [128][64], el = d*64   + (key ^ ((d&7)<<3))      (f16)
// P  LDS: per-wave [16][64],    el = row*64 + (col ^ ((row&7)<<3))    (f16)
// All XOR swizzles are the m214-verified byte^=(row&7)<<4 pattern.
// No inline asm; compiler owns all waitcnt ordering.
// SPLIT=1: 2-way KV split (512 blocks) + merge kernel; SPLIT=0: 256 blocks,
// normalized write, no workspace use.
// ---------------------------------------------------------------------------
template <bool SPLIT>
__global__ __launch_bounds__(256, 2)
void attn_fwd(const float* __restrict__ Qg, const float* __restrict__ Kg,
              const float* __restrict__ Vg, float* __restrict__ Og,
              float* __restrict__ O1, float2* __restrict__ ml0,
              float2* __restrict__ ml1)
{
    __shared__ __align__(16) f16 Kl[64 * 128];
    __shared__ __align__(16) f16 Vt[128 * 64];
    __shared__ __align__(16) f16 Pl[4][16 * 64];

    const int tid  = threadIdx.x;
    const int lane = tid & 63;
    const int w    = tid >> 6;
    const int c_   = lane & 15;   // A-frag row / D-frag col
    const int g    = lane >> 4;   // k-group

    // block decode
    const int L  = blockIdx.x;
    const int bb = L & 7;                       // batch -> XCD
    int qb, hv, t0, t1;
    if (SPLIT) {
        const int rem = L >> 3;
        qb = 31 - (rem >> 1);                   // LPT: longest first
        hv = rem & 1;
        const int T   = qb + 1;
        const int Th0 = (T + 1) >> 1;
        t0 = hv ? Th0 : 0;
        t1 = hv ? T : Th0;
    } else {
        qb = 31 - (L >> 3);
        hv = 0;
        t0 = 0;
        t1 = qb + 1;
    }

    const int qrow0 = qb * 64 + w * 16;

    // Q fragments, pre-scaled by 1/sqrt(D) * log2(e)
    const float qs = 0.08838834764831845f * 1.4426950408889634f;
    f16x8 qf[4];
    {
        const float* qp = Qg + (size_t)(bb * SS + qrow0 + c_) * DD;
#pragma unroll
        for (int kk = 0; kk < 4; ++kk) {
            const int d0 = kk * 32 + g * 8;
            f32x4 a = *(const f32x4*)(qp + d0);
            f32x4 b = *(const f32x4*)(qp + d0 + 4);
            f16x8 q;
#pragma unroll
            for (int i = 0; i < 4; ++i) {
                q[i]     = (f16)(a[i] * qs);
                q[i + 4] = (f16)(b[i] * qs);
            }
            qf[kk] = q;
        }
    }

    f32x4 Oa[8];
#pragma unroll
    for (int i = 0; i < 8; ++i) Oa[i] = (f32x4){0.f, 0.f, 0.f, 0.f};
    float mrun[4] = {-1e30f, -1e30f, -1e30f, -1e30f};
    float lrun[4] = {0.f, 0.f, 0.f, 0.f};

    f16* Pw = &Pl[w][0];

    // staging thread mappings
    const int krow = tid >> 5;      // K: row = krow + 8j
    const int kc4  = tid & 31;      // K: col quad
    const int vkg  = tid >> 5;      // V: key group (8 keys)
    const int vq   = tid & 31;      // V: d quad (d = vq*4 + dd)

    f32x4 kreg[8], vreg[8];

    if (t0 < t1) {
        {   // prefetch first tile
            const size_t gb = (size_t)(bb * SS + t0 * 64) * DD;
#pragma unroll
            for (int j = 0; j < 8; ++j)
                kreg[j] = *(const f32x4*)(Kg + gb + (krow + 8 * j) * DD + kc4 * 4);
#pragma unroll
            for (int i = 0; i < 8; ++i)
                vreg[i] = *(const f32x4*)(Vg + gb + (vkg * 8 + i) * DD + vq * 4);
        }

        for (int t = t0; t < t1; ++t) {
            __syncthreads();
            // ---- stage K (swizzled row-major) ----
#pragma unroll
            for (int j = 0; j < 8; ++j) {
                const int row = krow + 8 * j;
                const int el  = row * 128 + ((kc4 * 4) ^ ((row & 7) << 3));
                f32x4 v = kreg[j];
                ushort4 u;
                u.x = f2h(v[0]); u.y = f2h(v[1]); u.z = f2h(v[2]); u.w = f2h(v[3]);
                *(ushort4*)&Kl[el] = u;
            }
            // ---- stage V transposed (swizzled [128][64]) ----
#pragma unroll
            for (int dd = 0; dd < 4; ++dd) {
                const int d  = vq * 4 + dd;
                const int sw = (d & 7) << 3;
#pragma unroll
                for (int h = 0; h < 2; ++h) {
                    ushort4 u;
                    u.x = f2h(vreg[4 * h + 0][dd]);
                    u.y = f2h(vreg[4 * h + 1][dd]);
                    u.z = f2h(vreg[4 * h + 2][dd]);
                    u.w = f2h(vreg[4 * h + 3][dd]);
                    const int el = d * 64 + ((vkg * 8 + 4 * h) ^ sw);
                    *(ushort4*)&Vt[el] = u;
                }
            }
            __syncthreads();

            // ---- issue next tile's global loads (hide under compute) ----
            if (t + 1 < t1) {
                const size_t gb = (size_t)(bb * SS + (t + 1) * 64) * DD;
#pragma unroll
                for (int j = 0; j < 8; ++j)
                    kreg[j] = *(const f32x4*)(Kg + gb + (krow + 8 * j) * DD + kc4 * 4);
#pragma unroll
                for (int i = 0; i < 8; ++i)
                    vreg[i] = *(const f32x4*)(Vg + gb + (vkg * 8 + i) * DD + vq * 4);
            }

            const int kbase = t * 64;

            // ---- QK^T ----
            f32x4 s[4];
#pragma unroll
            for (int nb = 0; nb < 4; ++nb) {
                f32x4 acc = (f32x4){0.f, 0.f, 0.f, 0.f};
                const int row = c_ + nb * 16;
                const int sw  = (row & 7) << 3;
#pragma unroll
                for (int kk = 0; kk < 4; ++kk) {
                    f16x8 kb = *(const f16x8*)&Kl[row * 128 + ((kk * 32 + g * 8) ^ sw)];
                    acc = __builtin_amdgcn_mfma_f32_16x16x32_f16(qf[kk], kb, acc, 0, 0, 0);
                }
                s[nb] = acc;
            }

            // ---- causal mask (diagonal tile only) ----
            if (t == qb) {
#pragma unroll
                for (int nb = 0; nb < 4; ++nb)
#pragma unroll
                    for (int r = 0; r < 4; ++r) {
                        const int kj = kbase + nb * 16 + c_;
                        const int qi = qrow0 + g * 4 + r;
                        if (kj > qi) s[nb][r] = -1e30f;
                    }
            }

            // ---- online softmax (exp2 domain) ----
            float pm[4], sc[4];
#pragma unroll
            for (int r = 0; r < 4; ++r) {
                float v = fmaxf(fmaxf(s[0][r], s[1][r]), fmaxf(s[2][r], s[3][r]));
                v = fmaxf(v, __shfl_xor(v, 1));
                v = fmaxf(v, __shfl_xor(v, 2));
                v = fmaxf(v, __shfl_xor(v, 4));
                v = fmaxf(v, __shfl_xor(v, 8));
                pm[r] = v;
            }
#pragma unroll
            for (int r = 0; r < 4; ++r) {
                float mn = fmaxf(mrun[r], pm[r]);
                sc[r]   = fast_exp2(mrun[r] - mn);
                mrun[r] = mn;
            }
            float rs[4] = {0.f, 0.f, 0.f, 0.f};
            f16 pv16[4][4];
#pragma unroll
            for (int nb = 0; nb < 4; ++nb)
#pragma unroll
                for (int r = 0; r < 4; ++r) {
                    float pv = fast_exp2(s[nb][r] - mrun[r]);
                    rs[r] += pv;
                    pv16[nb][r] = (f16)pv;
                }
#pragma unroll
            for (int r = 0; r < 4; ++r) {
                float v = rs[r];
                v += __shfl_xor(v, 1);
                v += __shfl_xor(v, 2);
                v += __shfl_xor(v, 4);
                v += __shfl_xor(v, 8);
                lrun[r] = lrun[r] * sc[r] + v;
            }
#pragma unroll
            for (int dblk = 0; dblk < 8; ++dblk)
#pragma unroll
                for (int r = 0; r < 4; ++r) Oa[dblk][r] *= sc[r];

            // ---- P -> LDS (swizzled, per-wave) ----
#pragma unroll
            for (int nb = 0; nb < 4; ++nb)
#pragma unroll
                for (int r = 0; r < 4; ++r) {
                    const int row = g * 4 + r;
                    Pw[row * 64 + ((nb * 16 + c_) ^ ((row & 7) << 3))] = pv16[nb][r];
                }

            // ---- PV: A = P (from Pl), B = V (from transposed Vt) ----
#pragma unroll
            for (int ks = 0; ks < 2; ++ks) {
                f16x8 pa = *(const f16x8*)&Pw[c_ * 64 + ((ks * 32 + g * 8) ^ ((c_ & 7) << 3))];
#pragma unroll
                for (int dblk = 0; dblk < 8; ++dblk) {
                    const int d  = dblk * 16 + c_;
                    f16x8 vb = *(const f16x8*)&Vt[d * 64 + ((ks * 32 + g * 8) ^ ((d & 7) << 3))];
                    Oa[dblk] = __builtin_amdgcn_mfma_f32_16x16x32_f16(pa, vb, Oa[dblk], 0, 0, 0);
                }
            }
        }
    }

    // ---- epilogue ----
    if (SPLIT) {
        float*  od  = hv ? O1 : Og;
        float2* mld = hv ? ml1 : ml0;
#pragma unroll
        for (int r = 0; r < 4; ++r) {
            const int qrow = qrow0 + g * 4 + r;
            float* dst = od + (size_t)(bb * SS + qrow) * DD + c_;
#pragma unroll
            for (int dblk = 0; dblk < 8; ++dblk) dst[dblk * 16] = Oa[dblk][r];
            if (c_ == 0) mld[bb * SS + qrow] = make_float2(mrun[r], lrun[r]);
        }
    } else {
#pragma unroll
        for (int r = 0; r < 4; ++r) {
            const int qrow = qrow0 + g * 4 + r;
            float* dst = Og + (size_t)(bb * SS + qrow) * DD + c_;
            const float inv = 1.0f / lrun[r];
#pragma unroll
            for (int dblk = 0; dblk < 8; ++dblk) dst[dblk * 16] = Oa[dblk][r] * inv;
        }
    }
}

// ---------------------------------------------------------------------------
// Merge the two KV halves: out = (O0*e0 + O1*e1) / (l0*e0 + l1*e1)
// ---------------------------------------------------------------------------
__global__ __launch_bounds__(256)
void merge_kernel(float* __restrict__ out, const float* __restrict__ O1,
                  const float2* __restrict__ ml0, const float2* __restrict__ ml1)
{
    const int idx = blockIdx.x * 256 + threadIdx.x;  // float4 units
    const int row = idx >> 5;
    const float2 a = ml0[row];
    const float2 b = ml1[row];
    const float mm = fmaxf(a.x, b.x);
    const float e0 = fast_exp2(a.x - mm);
    const float e1 = fast_exp2(b.x - mm);
    const float inv = 1.0f / (a.y * e0 + b.y * e1);
    float4 o0 = ((const float4*)out)[idx];
    float4 o1 = ((const float4*)O1)[idx];
    float4 r;
    r.x = (o0.x * e0 + o1.x * e1) * inv;
    r.y = (o0.y * e0 + o1.y * e1) * inv;
    r.z = (o0.z * e0 + o1.z * e1) * inv;
    r.w = (o0.w * e0 + o1.w * e1) * inv;
    ((float4*)out)[idx] = r;
}

extern "C" void kernel_launch(void* const* d_in, const int* in_sizes, int n_in,
                              void* d_out, int out_size, void* d_ws, size_t ws_size,
                              hipStream_t stream)
{
    const float* Q = (const float*)d_in[0];
    const float* K = (const float*)d_in[1];
    const float* V = (const float*)d_in[2];
    float* out = (float*)d_out;

    const size_t O1_bytes = (size_t)BB * SS * DD * sizeof(float);   // 8 MB
    const size_t ml_bytes = (size_t)BB * SS * sizeof(float2);       // 128 KB
    const size_t need     = O1_bytes + 2 * ml_bytes;

    if (ws_size >= need) {
        float*  O1  = (float*)d_ws;
        float2* ml0 = (float2*)((char*)d_ws + O1_bytes);
        float2* ml1 = ml0 + (size_t)BB * SS;
        hipLaunchKernelGGL((attn_fwd<true>), dim3(512), dim3(256), 0, stream,
                           Q, K, V, out, O1, ml0, ml1);
        hipLaunchKernelGGL(merge_kernel, dim3(BB * SS * DD / 4 / 256), dim3(256),
                           0, stream, out, O1, ml0, ml1);
    } else {
        hipLaunchKernelGGL((attn_fwd<false>), dim3(256), dim3(256), 0, stream,
                           Q, K, V, out, (float*)nullptr,
                           (float2*)nullptr, (float2*)nullptr);
    }
}

// Round 3
// 105.720 us; speedup vs baseline: 1.1015x; 1.1015x over previous
//
#include <hip/hip_runtime.h>

#define BB 8
#define SS 2048
#define DD 128

typedef _Float16 f16;
typedef _Float16 f16x8 __attribute__((ext_vector_type(8)));
typedef float f32x4 __attribute__((ext_vector_type(4)));

// V-transpose LDS swizzle: spreads banks for BOTH the staging writes
// (d = vq*4+dd -> d>>3 spans 0..15) and the PV reads (d = dblk*16+c_).
#define SWV(d) ((((d) & 7) ^ (((d) >> 3) & 7)) << 3)

static __device__ __forceinline__ unsigned short f2h(float x) {
    f16 h = (f16)x;
    return __builtin_bit_cast(unsigned short, h);
}

static __device__ __forceinline__ float fast_exp2(float x) {
#if __has_builtin(__builtin_amdgcn_exp2f)
    return __builtin_amdgcn_exp2f(x);
#else
    return exp2f(x);
#endif
}

// ---------------------------------------------------------------------------
// Flash attention forward, causal. f16 MFMA 16x16x32, fp32 softmax/accum.
// 256 threads = 4 waves; each wave owns 16 q rows (QBLK=64 per block).
// NS-way KV split across blocks (grid = 8*32*NS); merge kernel combines.
// K  LDS: [64][128],  el = row*128 + (col ^ ((row&7)<<3))
// Vt LDS: [128][64],  el = d*64   + (key ^ SWV(d))
// P  LDS: per-wave [16][64], el = row*64 + (col ^ ((row&7)<<3))
// ---------------------------------------------------------------------------
template <int NS>
__global__ __launch_bounds__(256, 2)
void attn_fwd(const float* __restrict__ Qg, const float* __restrict__ Kg,
              const float* __restrict__ Vg, float* __restrict__ Og,
              float* __restrict__ Opart, float2* __restrict__ mlb)
{
    __shared__ __align__(16) f16 Kl[64 * 128];
    __shared__ __align__(16) f16 Vt[128 * 64];
    __shared__ __align__(16) f16 Pl[4][16 * 64];

    const int tid  = threadIdx.x;
    const int lane = tid & 63;
    const int w    = tid >> 6;
    const int c_   = lane & 15;   // key col (QK^T) / d col (PV out)
    const int g    = lane >> 4;

    // block decode: batch -> XCD; qb descending (LPT); split segment
    const int L   = blockIdx.x;
    const int bb  = L & 7;
    const int rem = L >> 3;
    const int qb  = 31 - (rem / NS);
    const int s   = rem % NS;
    const int T   = qb + 1;
    const int t0  = (T * s) / NS;
    const int t1  = (T * (s + 1)) / NS;

    const int qrow0 = qb * 64 + w * 16;

    // Q fragments, pre-scaled by 1/sqrt(D) * log2(e)
    const float qs = 0.08838834764831845f * 1.4426950408889634f;
    f16x8 qf[4];
    {
        const float* qp = Qg + (size_t)(bb * SS + qrow0 + c_) * DD;
#pragma unroll
        for (int kk = 0; kk < 4; ++kk) {
            const int d0 = kk * 32 + g * 8;
            f32x4 a = *(const f32x4*)(qp + d0);
            f32x4 b = *(const f32x4*)(qp + d0 + 4);
            f16x8 q;
#pragma unroll
            for (int i = 0; i < 4; ++i) {
                q[i]     = (f16)(a[i] * qs);
                q[i + 4] = (f16)(b[i] * qs);
            }
            qf[kk] = q;
        }
    }

    f32x4 Oa[8];
#pragma unroll
    for (int i = 0; i < 8; ++i) Oa[i] = (f32x4){0.f, 0.f, 0.f, 0.f};
    float mrun[4] = {-1e30f, -1e30f, -1e30f, -1e30f};
    float lpart[4] = {0.f, 0.f, 0.f, 0.f};   // per-lane partial l (reduced at end)

    f16* Pw = &Pl[w][0];

    // staging thread mappings
    const int krow = tid >> 5;      // K: row = krow + 8j
    const int kc4  = tid & 31;      // K: col quad
    const int vkg  = tid >> 5;      // V: key group (8 keys)
    const int vq   = tid & 31;      // V: d quad (d = vq*4 + dd)

    f32x4 kreg[8], vreg[8];

    if (t0 < t1) {
        {   // prefetch first tile
            const size_t gb = (size_t)(bb * SS + t0 * 64) * DD;
#pragma unroll
            for (int j = 0; j < 8; ++j)
                kreg[j] = *(const f32x4*)(Kg + gb + (krow + 8 * j) * DD + kc4 * 4);
#pragma unroll
            for (int i = 0; i < 8; ++i)
                vreg[i] = *(const f32x4*)(Vg + gb + (vkg * 8 + i) * DD + vq * 4);
        }

        for (int t = t0; t < t1; ++t) {
            __syncthreads();
            // ---- stage K (swizzled row-major) ----
#pragma unroll
            for (int j = 0; j < 8; ++j) {
                const int row = krow + 8 * j;
                const int el  = row * 128 + ((kc4 * 4) ^ ((row & 7) << 3));
                f32x4 v = kreg[j];
                ushort4 u;
                u.x = f2h(v[0]); u.y = f2h(v[1]); u.z = f2h(v[2]); u.w = f2h(v[3]);
                *(ushort4*)&Kl[el] = u;
            }
            // ---- stage V transposed (bank-spread swizzle) ----
#pragma unroll
            for (int dd = 0; dd < 4; ++dd) {
                const int d  = vq * 4 + dd;
                const int sw = SWV(d);
#pragma unroll
                for (int h = 0; h < 2; ++h) {
                    ushort4 u;
                    u.x = f2h(vreg[4 * h + 0][dd]);
                    u.y = f2h(vreg[4 * h + 1][dd]);
                    u.z = f2h(vreg[4 * h + 2][dd]);
                    u.w = f2h(vreg[4 * h + 3][dd]);
                    const int el = d * 64 + ((vkg * 8 + 4 * h) ^ sw);
                    *(ushort4*)&Vt[el] = u;
                }
            }
            __syncthreads();

            // ---- issue next tile's global loads (hide under compute) ----
            if (t + 1 < t1) {
                const size_t gb = (size_t)(bb * SS + (t + 1) * 64) * DD;
#pragma unroll
                for (int j = 0; j < 8; ++j)
                    kreg[j] = *(const f32x4*)(Kg + gb + (krow + 8 * j) * DD + kc4 * 4);
#pragma unroll
                for (int i = 0; i < 8; ++i)
                    vreg[i] = *(const f32x4*)(Vg + gb + (vkg * 8 + i) * DD + vq * 4);
            }

            const int kbase = t * 64;

            // ---- QK^T ----
            f32x4 s4[4];
            __builtin_amdgcn_s_setprio(1);
#pragma unroll
            for (int nb = 0; nb < 4; ++nb) {
                f32x4 acc = (f32x4){0.f, 0.f, 0.f, 0.f};
                const int row = c_ + nb * 16;
                const int sw  = (row & 7) << 3;
#pragma unroll
                for (int kk = 0; kk < 4; ++kk) {
                    f16x8 kb = *(const f16x8*)&Kl[row * 128 + ((kk * 32 + g * 8) ^ sw)];
                    acc = __builtin_amdgcn_mfma_f32_16x16x32_f16(qf[kk], kb, acc, 0, 0, 0);
                }
                s4[nb] = acc;
            }
            __builtin_amdgcn_s_setprio(0);

            // ---- causal mask (diagonal tile only) ----
            if (t == qb) {
#pragma unroll
                for (int nb = 0; nb < 4; ++nb)
#pragma unroll
                    for (int r = 0; r < 4; ++r) {
                        const int kj = kbase + nb * 16 + c_;
                        const int qi = qrow0 + g * 4 + r;
                        if (kj > qi) s4[nb][r] = -1e30f;
                    }
            }

            // ---- online softmax (exp2 domain), defer-max THR=8 ----
            float pm[4], sc[4];
#pragma unroll
            for (int r = 0; r < 4; ++r) {
                float v = fmaxf(fmaxf(s4[0][r], s4[1][r]), fmaxf(s4[2][r], s4[3][r]));
                v = fmaxf(v, __shfl_xor(v, 1));
                v = fmaxf(v, __shfl_xor(v, 2));
                v = fmaxf(v, __shfl_xor(v, 4));
                v = fmaxf(v, __shfl_xor(v, 8));
                pm[r] = v;
            }
#pragma unroll
            for (int r = 0; r < 4; ++r) {
                const bool keep = (pm[r] - mrun[r] <= 8.0f);
                const float mn  = keep ? mrun[r] : pm[r];
                sc[r]   = keep ? 1.0f : fast_exp2(mrun[r] - pm[r]);
                mrun[r] = mn;
            }
            float rs[4] = {0.f, 0.f, 0.f, 0.f};
            f16 pv16[4][4];
#pragma unroll
            for (int nb = 0; nb < 4; ++nb)
#pragma unroll
                for (int r = 0; r < 4; ++r) {
                    float pv = fast_exp2(s4[nb][r] - mrun[r]);
                    rs[r] += pv;
                    pv16[nb][r] = (f16)pv;
                }
            const float scmin = fminf(fminf(sc[0], sc[1]), fminf(sc[2], sc[3]));
            if (scmin < 1.0f) {
#pragma unroll
                for (int dblk = 0; dblk < 8; ++dblk)
#pragma unroll
                    for (int r = 0; r < 4; ++r) Oa[dblk][r] *= sc[r];
            }
#pragma unroll
            for (int r = 0; r < 4; ++r) lpart[r] = lpart[r] * sc[r] + rs[r];

            // ---- P -> LDS (swizzled, per-wave) ----
#pragma unroll
            for (int nb = 0; nb < 4; ++nb)
#pragma unroll
                for (int r = 0; r < 4; ++r) {
                    const int row = g * 4 + r;
                    Pw[row * 64 + ((nb * 16 + c_) ^ ((row & 7) << 3))] = pv16[nb][r];
                }

            // ---- PV: A = P, B = Vt ----
#pragma unroll
            for (int ks = 0; ks < 2; ++ks) {
                f16x8 pa = *(const f16x8*)&Pw[c_ * 64 + ((ks * 32 + g * 8) ^ ((c_ & 7) << 3))];
                __builtin_amdgcn_s_setprio(1);
#pragma unroll
                for (int dblk = 0; dblk < 8; ++dblk) {
                    const int d  = dblk * 16 + c_;
                    f16x8 vb = *(const f16x8*)&Vt[d * 64 + ((ks * 32 + g * 8) ^ SWV(d))];
                    Oa[dblk] = __builtin_amdgcn_mfma_f32_16x16x32_f16(pa, vb, Oa[dblk], 0, 0, 0);
                }
                __builtin_amdgcn_s_setprio(0);
            }
        }
    }

    // ---- reduce deferred l across the 16 key-lanes ----
    float lrun[4];
#pragma unroll
    for (int r = 0; r < 4; ++r) {
        float v = lpart[r];
        v += __shfl_xor(v, 1);
        v += __shfl_xor(v, 2);
        v += __shfl_xor(v, 4);
        v += __shfl_xor(v, 8);
        lrun[r] = v;
    }

    // ---- epilogue ----
    if (NS == 1) {
#pragma unroll
        for (int r = 0; r < 4; ++r) {
            const int qrow = qrow0 + g * 4 + r;
            float* dst = Og + (size_t)(bb * SS + qrow) * DD + c_;
            const float inv = 1.0f / lrun[r];
#pragma unroll
            for (int dblk = 0; dblk < 8; ++dblk) dst[dblk * 16] = Oa[dblk][r] * inv;
        }
    } else {
        float*  od  = (s == 0) ? Og : (Opart + (size_t)(s - 1) * BB * SS * DD);
        float2* mld = mlb + (size_t)s * BB * SS;
#pragma unroll
        for (int r = 0; r < 4; ++r) {
            const int qrow = qrow0 + g * 4 + r;
            float* dst = od + (size_t)(bb * SS + qrow) * DD + c_;
#pragma unroll
            for (int dblk = 0; dblk < 8; ++dblk) dst[dblk * 16] = Oa[dblk][r];
            if (c_ == 0) mld[bb * SS + qrow] = make_float2(mrun[r], lrun[r]);
        }
    }
}

// ---------------------------------------------------------------------------
// Merge NS KV-split partials: out = (sum Oi*ei) / (sum li*ei)
// ---------------------------------------------------------------------------
template <int NS>
__global__ __launch_bounds__(256)
void merge_kernel(float* __restrict__ out, const float* __restrict__ Opart,
                  const float2* __restrict__ mlb)
{
    const int idx = blockIdx.x * 256 + threadIdx.x;  // float4 units
    const int row = idx >> 5;
    float2 ml[NS];
#pragma unroll
    for (int i = 0; i < NS; ++i) ml[i] = mlb[(size_t)i * BB * SS + row];
    float mm = ml[0].x;
#pragma unroll
    for (int i = 1; i < NS; ++i) mm = fmaxf(mm, ml[i].x);
    float e[NS], den = 0.f;
#pragma unroll
    for (int i = 0; i < NS; ++i) {
        e[i] = fast_exp2(ml[i].x - mm);
        den += ml[i].y * e[i];
    }
    const float inv = 1.0f / den;
    float4 o = ((const float4*)out)[idx];
    float4 acc;
    acc.x = o.x * e[0]; acc.y = o.y * e[0];
    acc.z = o.z * e[0]; acc.w = o.w * e[0];
#pragma unroll
    for (int i = 1; i < NS; ++i) {
        float4 p = ((const float4*)(Opart + (size_t)(i - 1) * BB * SS * DD))[idx];
        acc.x += p.x * e[i]; acc.y += p.y * e[i];
        acc.z += p.z * e[i]; acc.w += p.w * e[i];
    }
    acc.x *= inv; acc.y *= inv; acc.z *= inv; acc.w *= inv;
    ((float4*)out)[idx] = acc;
}

extern "C" void kernel_launch(void* const* d_in, const int* in_sizes, int n_in,
                              void* d_out, int out_size, void* d_ws, size_t ws_size,
                              hipStream_t stream)
{
    const float* Q = (const float*)d_in[0];
    const float* K = (const float*)d_in[1];
    const float* V = (const float*)d_in[2];
    float* out = (float*)d_out;

    const size_t OB = (size_t)BB * SS * DD * sizeof(float);   // 8 MB
    const size_t MB_ = (size_t)BB * SS * sizeof(float2);      // 128 KB
    const int mergeGrid = BB * SS * DD / 4 / 256;             // 2048

    const size_t need4 = 3 * OB + 4 * MB_;
    const size_t need2 = 1 * OB + 2 * MB_;

    if (ws_size >= need4) {
        float*  Op  = (float*)d_ws;
        float2* mlb = (float2*)((char*)d_ws + 3 * OB);
        hipLaunchKernelGGL((attn_fwd<4>), dim3(8 * 32 * 4), dim3(256), 0, stream,
                           Q, K, V, out, Op, mlb);
        hipLaunchKernelGGL((merge_kernel<4>), dim3(mergeGrid), dim3(256), 0, stream,
                           out, Op, mlb);
    } else if (ws_size >= need2) {
        float*  Op  = (float*)d_ws;
        float2* mlb = (float2*)((char*)d_ws + 1 * OB);
        hipLaunchKernelGGL((attn_fwd<2>), dim3(8 * 32 * 2), dim3(256), 0, stream,
                           Q, K, V, out, Op, mlb);
        hipLaunchKernelGGL((merge_kernel<2>), dim3(mergeGrid), dim3(256), 0, stream,
                           out, Op, mlb);
    } else {
        hipLaunchKernelGGL((attn_fwd<1>), dim3(8 * 32), dim3(256), 0, stream,
                           Q, K, V, out, (float*)nullptr, (float2*)nullptr);
    }
}